// Round 8
// baseline (110.996 us; speedup 1.0000x reference)
//
#include <hip/hip_runtime.h>
#include <hip/hip_fp16.h>

// Problem constants (match reference)
constexpr int kHW = 1024 * 1024;
constexpr int kChunksPerImage = kHW / 4;            // 262144 = 2^18
constexpr int kM3 = 17 * 17 * 17;                   // 4913 cells

// Packed-table layout in d_ws (uints):
//   [0,      4928)  pA[cell] = fp16(c0) | fp16(c1)<<16
//   [4928,   9856)  pB[cell] = fp16(c2[cell]) | fp16(c2[cell+1])<<16
//   [9856,  10048)  p1[c*64+j] = fp16(l[j]) | fp16(l[j+1])<<16
constexpr int kPA   = 4928;
constexpr int kLdsU = 2 * kPA;                      // 9856 uints -> 39,424 B LDS
constexpr int kP1   = kLdsU;

constexpr int kBlock = 512;
constexpr int kGrid  = 2048;                        // 1 float4-chunk per thread

__device__ __forceinline__ float2 h2f2(unsigned int u) {
    return __half22float2(*reinterpret_cast<__half2*>(&u));
}
__device__ __forceinline__ unsigned int packh2(float a, float b) {
    __half2 h = __floats2half2_rn(a, b);
    return *reinterpret_cast<unsigned int*>(&h);
}

// ---------------- pre-pass: build packed tables in d_ws ----------------
__global__ void pack_kernel(const float* __restrict__ lut1d,
                            const float* __restrict__ lut3d,
                            unsigned int* __restrict__ ws) {
    const int i = blockIdx.x * 256 + threadIdx.x;   // 64 blocks x 256 = 16384
    if (i < kPA) {
        unsigned int a = 0, b = 0;
        if (i < kM3) {
            float c0 = lut3d[3 * i], c1 = lut3d[3 * i + 1], c2 = lut3d[3 * i + 2];
            int j = (i + 1 < kM3) ? i + 1 : i;
            float c2n = lut3d[3 * j + 2];
            a = packh2(c0, c1);
            b = packh2(c2, c2n);
        }
        ws[i]       = a;
        ws[kPA + i] = b;
    }
    if (i < 192) {
        int c = i >> 6, j = i & 63;
        float l0 = lut1d[(c << 6) + j];
        float l1 = lut1d[(c << 6) + (j < 63 ? j + 1 : 63)];
        ws[kP1 + i] = packh2(l0, l1);
    }
}

// 1D LUT lerp, table pair in a VGPR, gathered by conflict-free ds_bpermute.
// No clamps: input v is uniform [0,1); if v*63 rounds up to exactly 63.0,
// table[63]=(l63,l63) with f=0 gives the exact answer.
__device__ __forceinline__ float apply1d_bp(unsigned int treg, float v) {
    float xs = v * 63.0f;
    int i0 = (int)xs;
    float f = xs - (float)i0;
    unsigned int pair =
        (unsigned int)__builtin_amdgcn_ds_bpermute(i0 << 2, (int)treg);
    float2 p = h2f2(pair);
    return fmaf(f, p.y - p.x, p.x);
}

struct F3 { float x, y, z; };

// Trilinear: (c0,c1) interpolated entirely in packed __half2 (hfma2 chains),
// c2 in f32. Cuts per-corner unpack cvts and halves the merge fma count.
__device__ __forceinline__ F3 tri3d(const unsigned int* __restrict__ sA,
                                    const unsigned int* __restrict__ sB,
                                    float yr, float yg, float yb) {
    float xr = yr * 16.0f, xg = yg * 16.0f, xb = yb * 16.0f;
    int ir = min((int)xr, 15);
    int ig = min((int)xg, 15);
    int ib = min((int)xb, 15);
    float fr = xr - (float)ir;
    float fg = xg - (float)ig;
    float fb = xb - (float)ib;

    const __half2 fb2 = __float2half2_rn(fb);
    const __half2 fg2 = __float2half2_rn(fg);
    const __half2 fr2 = __float2half2_rn(fr);

    const int cell = (ir * 17 + ig) * 17 + ib;      // db=1, dg=17, dr=289

    // Per (r,g) corner pair: ds_read2_b32 (both b-corners' c0c1) + ds_read_b32
    // (paired c2). xy-lerp along b in packed half2: 2 VALU. z-lerp in f32.
    __half2 xy[4]; float z[4];
    #pragma unroll
    for (int t = 0; t < 4; ++t) {
        const int c = cell + (t & 1) * 289 + (t >> 1) * 17;
        __half2 A0 = *reinterpret_cast<const __half2*>(sA + c);
        __half2 A1 = *reinterpret_cast<const __half2*>(sA + c + 1);
        float2  Bc = h2f2(sB[c]);
        xy[t] = __hfma2(fb2, __hsub2(A1, A0), A0);
        z[t]  = fmaf(fb, Bc.y - Bc.x, Bc.x);
    }
    // t: 0=(r0,g0) 1=(r1,g0) 2=(r0,g1) 3=(r1,g1)
    __half2 g0 = __hfma2(fg2, __hsub2(xy[2], xy[0]), xy[0]);
    __half2 g1 = __hfma2(fg2, __hsub2(xy[3], xy[1]), xy[1]);
    float   h0 = fmaf(fg, z[2] - z[0], z[0]);
    float   h1 = fmaf(fg, z[3] - z[1], z[1]);

    __half2 rxy = __hfma2(fr2, __hsub2(g1, g0), g0);
    float2  oxy = __half22float2(rxy);

    F3 r;
    r.x = oxy.x;
    r.y = oxy.y;
    r.z = fmaf(fr, h1 - h0, h0);
    return r;
}

// NOTE: no min-waves bound — __launch_bounds__(512,8) forced VGPR=32 and
// caused scratch spill (R4/R5: FETCH 3.5x, WRITE 6.3x, kernel 142 us).
__global__ __launch_bounds__(kBlock) void lut_apply_kernel(
    const float* __restrict__ x,
    const unsigned int* __restrict__ ws,
    float* __restrict__ out)
{
    __shared__ uint4 ldsv[kLdsU / 4];               // 39,424 B -> 4 blocks/CU
    unsigned int* lds = (unsigned int*)ldsv;

    // ---- Hoisted global loads: issue before the LDS fill so input HBM
    // latency overlaps the fill + barrier. ----
    const int q   = blockIdx.x * kBlock + threadIdx.x;   // [0, 2^20)
    const int b   = q >> 18;
    const int rem = q & (kChunksPerImage - 1);
    const size_t base = (size_t)(3 * b) * kHW + 4 * (size_t)rem;

    const float4 r4 = *(const float4*)(x + base);
    const float4 g4 = *(const float4*)(x + base + kHW);
    const float4 b4 = *(const float4*)(x + base + 2 * kHW);

    // Per-wave 1D table in registers (lane j holds pair (l[j], l[j+1])).
    const int lane = threadIdx.x & 63;
    const unsigned int t0 = ws[kP1 + lane];
    const unsigned int t1 = ws[kP1 + 64 + lane];
    const unsigned int t2 = ws[kP1 + 128 + lane];

    // Flat vectorized fill of the packed 3D tables (pre-packed by pack_kernel).
    const uint4* wsv = (const uint4*)ws;
    #pragma unroll 1
    for (int i = threadIdx.x; i < kLdsU / 4; i += kBlock) ldsv[i] = wsv[i];
    __syncthreads();

    const unsigned int* sA = lds;
    const unsigned int* sB = lds + kPA;

    const float rin[4] = {r4.x, r4.y, r4.z, r4.w};
    const float gin[4] = {g4.x, g4.y, g4.z, g4.w};
    const float bin[4] = {b4.x, b4.y, b4.z, b4.w};
    float ro[4], go[4], bo[4];

    #pragma unroll
    for (int k = 0; k < 4; ++k) {
        float yr = apply1d_bp(t0, rin[k]);
        float yg = apply1d_bp(t1, gin[k]);
        float yb = apply1d_bp(t2, bin[k]);
        yr = fminf(fmaxf(yr, 0.0f), 1.0f);
        yg = fminf(fmaxf(yg, 0.0f), 1.0f);
        yb = fminf(fmaxf(yb, 0.0f), 1.0f);

        F3 v = tri3d(sA, sB, yr, yg, yb);
        ro[k] = v.x; go[k] = v.y; bo[k] = v.z;
    }

    *(float4*)(out + base)           = make_float4(ro[0], ro[1], ro[2], ro[3]);
    *(float4*)(out + base + kHW)     = make_float4(go[0], go[1], go[2], go[3]);
    *(float4*)(out + base + 2 * kHW) = make_float4(bo[0], bo[1], bo[2], bo[3]);
}

extern "C" void kernel_launch(void* const* d_in, const int* in_sizes, int n_in,
                              void* d_out, int out_size, void* d_ws, size_t ws_size,
                              hipStream_t stream) {
    const float* x     = (const float*)d_in[0];
    const float* lut1d = (const float*)d_in[1];
    const float* lut3d = (const float*)d_in[2];
    float* out = (float*)d_out;
    unsigned int* ws = (unsigned int*)d_ws;

    hipLaunchKernelGGL(pack_kernel, dim3(64), dim3(256), 0, stream,
                       lut1d, lut3d, ws);
    hipLaunchKernelGGL(lut_apply_kernel, dim3(kGrid), dim3(kBlock), 0, stream,
                       x, ws, out);
}